// Round 1
// baseline (206.156 us; speedup 1.0000x reference)
//
#include <hip/hip_runtime.h>
#include <hip/hip_bf16.h>

#define BB 8
#define NN 20
#define KK 5
#define DD 230
#define NQ 200

// ---------------- transpose fc_w (230x230) -> Wt[j][i] = w[i][j] ----------------
__global__ void k_transpose(const float* __restrict__ w, float* __restrict__ wt) {
    int idx = blockIdx.x * 256 + threadIdx.x;
    if (idx < DD * DD) {
        int i = idx / DD, j = idx % DD;
        wt[j * DD + i] = w[i * DD + j];
    }
}

// ---------------- fc: out[r][c] = (sum_k in[r][k] * wt[k][c] + bias[c]) * scale ----
// grid = rows/4 blocks, block = 256 (lanes over c)
__global__ void k_fc(const float* __restrict__ in, const float* __restrict__ wt,
                     const float* __restrict__ bias, float* __restrict__ out,
                     float scale) {
    const int c = threadIdx.x;
    const int cc = c < DD ? c : DD - 1;
    const int r0 = blockIdx.x * 4;
    const float* i0 = in + (size_t)r0 * DD;
    const float* i1 = i0 + DD;
    const float* i2 = i1 + DD;
    const float* i3 = i2 + DD;
    float a0 = 0.f, a1 = 0.f, a2 = 0.f, a3 = 0.f;
    for (int k = 0; k < DD; k++) {
        float w = wt[k * DD + cc];
        a0 = fmaf(i0[k], w, a0);
        a1 = fmaf(i1[k], w, a1);
        a2 = fmaf(i2[k], w, a2);
        a3 = fmaf(i3[k], w, a3);
    }
    if (c < DD) {
        float bb = bias[c];
        out[(size_t)(r0 + 0) * DD + c] = (a0 + bb) * scale;
        out[(size_t)(r0 + 1) * DD + c] = (a1 + bb) * scale;
        out[(size_t)(r0 + 2) * DD + c] = (a2 + bb) * scale;
        out[(size_t)(r0 + 3) * DD + c] = (a3 + bb) * scale;
    }
}

// ---------------- conv chain: score700[img][d] -------------------------------------
// grid = 160 imgs * 4 d-chunks, block = 256 (4 waves)
// per block: one (b,n) image, 64 d-columns. conv is independent per d.
__global__ void k_conv(const float* __restrict__ S,
                       const float* __restrict__ w1, const float* __restrict__ b1,
                       const float* __restrict__ w2, const float* __restrict__ b2,
                       const float* __restrict__ wf, const float* __restrict__ bf,
                       float* __restrict__ score) {
    __shared__ float x1s[32 * 5][64];   // [c*5+i][lane]
    __shared__ float xfp[4][64];
    const int tid = threadIdx.x;
    const int lane = tid & 63, wv = tid >> 6;
    const int img = blockIdx.x >> 2, chunk = blockIdx.x & 3;
    const int d = chunk * 64 + lane;
    const bool act = d < DD;

    // load input column S[img][j][d], j=0..4
    float in[5];
    const float* sp = S + (size_t)img * KK * DD + d;
#pragma unroll
    for (int j = 0; j < 5; j++) in[j] = act ? sp[j * DD] : 0.f;

    // phase 1: conv1 for channels c = wv*8 .. wv*8+7
#pragma unroll
    for (int ccc = 0; ccc < 8; ccc++) {
        int c = wv * 8 + ccc;
        float wl[5];
#pragma unroll
        for (int t = 0; t < 5; t++) wl[t] = w1[c * 5 + t];
        float bb = b1[c];
#pragma unroll
        for (int i = 0; i < 5; i++) {
            float a = bb;
#pragma unroll
            for (int t = 0; t < 5; t++) {
                int j = i + t - 2;
                if (j >= 0 && j < 5) a = fmaf(wl[t], in[j], a);
            }
            x1s[c * 5 + i][lane] = fmaxf(a, 0.f);
        }
    }
    __syncthreads();

    // phase 2: conv2 for o in [wv*16, wv*16+16) in 2 chunks of 8, + convf partial
    float xf = 0.f;
#pragma unroll
    for (int oc = 0; oc < 2; oc++) {
        const int ob = wv * 16 + oc * 8;
        float acc[8][5];
#pragma unroll
        for (int oo = 0; oo < 8; oo++) {
            float bb = b2[ob + oo];
#pragma unroll
            for (int i = 0; i < 5; i++) acc[oo][i] = bb;
        }
        for (int c = 0; c < 32; c++) {
            float xv[5];
#pragma unroll
            for (int j = 0; j < 5; j++) xv[j] = x1s[c * 5 + j][lane];
#pragma unroll
            for (int oo = 0; oo < 8; oo++) {
                const float* wp = w2 + ((size_t)(ob + oo) * 32 + c) * 5;
#pragma unroll
                for (int t = 0; t < 5; t++) {
                    float wv2 = wp[t];
#pragma unroll
                    for (int i = 0; i < 5; i++) {
                        int j = i + t - 2;
                        if (j >= 0 && j < 5) acc[oo][i] = fmaf(wv2, xv[j], acc[oo][i]);
                    }
                }
            }
        }
        // convf contribution (stride 5 -> taps are exactly positions 0..4)
#pragma unroll
        for (int oo = 0; oo < 8; oo++) {
            const float* wfp = wf + (ob + oo) * 5;
#pragma unroll
            for (int t = 0; t < 5; t++)
                xf = fmaf(wfp[t], fmaxf(acc[oo][t], 0.f), xf);
        }
    }
    xfp[wv][lane] = xf;
    __syncthreads();
    if (wv == 0 && act) {
        float v = bf[0] + xfp[0][lane] + xfp[1][lane] + xfp[2][lane] + xfp[3][lane];
        score[(size_t)img * DD + d] = fmaxf(v, 0.f) * 700.f;
    }
}

// ---------------- attention logits: L[b,q,n,k] = sum_d tanh(Sf*Qf) ------------------
// Sf is pre-scaled by 2*log2(e). grid = B*NQ blocks, block = 256 (4 waves),
// each wave handles 25 of the 100 (n,k) pairs; lanes over d.
__global__ void k_attl(const float* __restrict__ Sf, const float* __restrict__ Qf,
                       float* __restrict__ L) {
    const int tid = threadIdx.x, lane = tid & 63, wv = tid >> 6;
    const int bq = blockIdx.x;
    const int b = bq / NQ;
    float qr[4];
    const float* qp = Qf + (size_t)bq * DD;
#pragma unroll
    for (int i = 0; i < 4; i++) {
        int d = lane + 64 * i;
        qr[i] = (d < DD) ? qp[d] : 0.f;
    }
    const float* sfb = Sf + (size_t)b * NN * KK * DD;
    for (int j = 0; j < 25; j++) {
        int idx = wv * 25 + j;   // n*5+k
        const float* sp = sfb + (size_t)idx * DD;
        float acc = 0.f;
#pragma unroll
        for (int i = 0; i < 4; i++) {
            int d = lane + 64 * i;
            float s = (d < DD) ? sp[d] : 0.f;
            float x = s * qr[i];                       // 2*log2e*Sf*Qf
            float e = __builtin_amdgcn_exp2f(x);
            float th = 1.f - 2.f * __builtin_amdgcn_rcpf(e + 1.f);
            acc += th;
        }
#pragma unroll
        for (int off = 32; off > 0; off >>= 1) acc += __shfl_xor(acc, off, 64);
        if (lane == 0) L[(size_t)bq * (NN * KK) + idx] = acc;
    }
}

// ---------------- final: softmax(K) + einsum + weighted L2 --------------------------
// grid = B*NQ blocks, block = 256 (4 waves), wave handles 5 n's; lanes over d.
__global__ void k_final(const float* __restrict__ L, const float* __restrict__ S,
                        const float* __restrict__ Q, const float* __restrict__ sc,
                        float* __restrict__ out) {
    const int tid = threadIdx.x, lane = tid & 63, wv = tid >> 6;
    const int bq = blockIdx.x;
    const int b = bq / NQ;
    const float LOG2E = 1.4426950408889634f;
    float qr[4];
    const float* qp = Q + (size_t)bq * DD;
#pragma unroll
    for (int i = 0; i < 4; i++) {
        int d = lane + 64 * i;
        qr[i] = (d < DD) ? qp[d] : 0.f;
    }
    for (int jn = 0; jn < 5; jn++) {
        int n = wv * 5 + jn;
        const float* lp = L + (size_t)bq * (NN * KK) + n * 5;
        float v0 = lp[0], v1 = lp[1], v2 = lp[2], v3 = lp[3], v4 = lp[4];
        float m = fmaxf(fmaxf(fmaxf(v0, v1), fmaxf(v2, v3)), v4);
        float e0 = __builtin_amdgcn_exp2f((v0 - m) * LOG2E);
        float e1 = __builtin_amdgcn_exp2f((v1 - m) * LOG2E);
        float e2 = __builtin_amdgcn_exp2f((v2 - m) * LOG2E);
        float e3 = __builtin_amdgcn_exp2f((v3 - m) * LOG2E);
        float e4 = __builtin_amdgcn_exp2f((v4 - m) * LOG2E);
        float inv = __builtin_amdgcn_rcpf(e0 + e1 + e2 + e3 + e4);
        float a0 = e0 * inv, a1 = e1 * inv, a2 = e2 * inv, a3 = e3 * inv, a4 = e4 * inv;
        const float* spn = S + (size_t)(b * NN + n) * KK * DD;
        const float* scp = sc + (size_t)(b * NN + n) * DD;
        float acc = 0.f;
#pragma unroll
        for (int i = 0; i < 4; i++) {
            int d = lane + 64 * i;
            if (d < DD) {
                float rep = a0 * spn[d] + a1 * spn[DD + d] + a2 * spn[2 * DD + d]
                          + a3 * spn[3 * DD + d] + a4 * spn[4 * DD + d];
                float df = rep - qr[i];
                acc = fmaf(df * df, scp[d], acc);
            }
        }
#pragma unroll
        for (int off = 32; off > 0; off >>= 1) acc += __shfl_xor(acc, off, 64);
        if (lane == 0) out[(size_t)bq * NN + n] = -acc;
    }
}

extern "C" void kernel_launch(void* const* d_in, const int* in_sizes, int n_in,
                              void* d_out, int out_size, void* d_ws, size_t ws_size,
                              hipStream_t stream) {
    const float* S       = (const float*)d_in[0];
    const float* Q       = (const float*)d_in[1];
    const float* fc_w    = (const float*)d_in[2];
    const float* fc_b    = (const float*)d_in[3];
    const float* conv1_w = (const float*)d_in[4];
    const float* conv1_b = (const float*)d_in[5];
    const float* conv2_w = (const float*)d_in[6];
    const float* conv2_b = (const float*)d_in[7];
    const float* convf_w = (const float*)d_in[8];
    const float* convf_b = (const float*)d_in[9];
    float* out = (float*)d_out;

    float* ws = (float*)d_ws;
    float* Wt = ws;                 // 52912 (230*230 rounded to /4)
    float* Sf = Wt + 52912;         // 184000
    float* Qf = Sf + 184000;        // 368000
    float* sc = Qf + 368000;        // 36800
    float* L  = sc + 36800;         // 160000

    const float TANH_SCALE = 2.8853900817779268f;  // 2*log2(e)

    k_transpose<<<208, 256, 0, stream>>>(fc_w, Wt);
    k_fc<<<(BB * NN * KK) / 4, 256, 0, stream>>>(S, Wt, fc_b, Sf, TANH_SCALE);
    k_fc<<<(BB * NQ) / 4, 256, 0, stream>>>(Q, Wt, fc_b, Qf, 1.0f);
    k_conv<<<BB * NN * 4, 256, 0, stream>>>(S, conv1_w, conv1_b, conv2_w, conv2_b,
                                            convf_w, convf_b, sc);
    k_attl<<<BB * NQ, 256, 0, stream>>>(Sf, Qf, L);
    k_final<<<BB * NQ, 256, 0, stream>>>(L, S, Q, sc, out);
    hipMemcpyAsync(out + (size_t)BB * NQ * NN, S,
                   (size_t)BB * NN * KK * DD * sizeof(float),
                   hipMemcpyDeviceToDevice, stream);
}

// Round 2
// 124.038 us; speedup vs baseline: 1.6620x; 1.6620x over previous
//
#include <hip/hip_runtime.h>
#include <hip/hip_bf16.h>

#define BB 8
#define NN 20
#define KK 5
#define DD 230
#define NQ 200

// ---------------- transpose fc_w (230x230) -> Wt[j][i] = w[i][j] ----------------
__global__ void k_transpose(const float* __restrict__ w, float* __restrict__ wt) {
    int idx = blockIdx.x * 256 + threadIdx.x;
    if (idx < DD * DD) {
        int i = idx / DD, j = idx % DD;
        wt[j * DD + i] = w[i * DD + j];
    }
}

// ---------------- fc: out[r][c] = (sum_k in[r][k] * wt[k][c] + bias[c]) * scale ----
__global__ void k_fc(const float* __restrict__ in, const float* __restrict__ wt,
                     const float* __restrict__ bias, float* __restrict__ out,
                     float scale) {
    const int c = threadIdx.x;
    const int cc = c < DD ? c : DD - 1;
    const int r0 = blockIdx.x * 4;
    const float* i0 = in + (size_t)r0 * DD;
    const float* i1 = i0 + DD;
    const float* i2 = i1 + DD;
    const float* i3 = i2 + DD;
    float a0 = 0.f, a1 = 0.f, a2 = 0.f, a3 = 0.f;
    for (int k = 0; k < DD; k++) {
        float w = wt[k * DD + cc];
        a0 = fmaf(i0[k], w, a0);
        a1 = fmaf(i1[k], w, a1);
        a2 = fmaf(i2[k], w, a2);
        a3 = fmaf(i3[k], w, a3);
    }
    if (c < DD) {
        float bb = bias[c];
        out[(size_t)(r0 + 0) * DD + c] = (a0 + bb) * scale;
        out[(size_t)(r0 + 1) * DD + c] = (a1 + bb) * scale;
        out[(size_t)(r0 + 2) * DD + c] = (a2 + bb) * scale;
        out[(size_t)(r0 + 3) * DD + c] = (a3 + bb) * scale;
    }
}

// ---------------- conv chain: score700[img][d] -------------------------------------
// grid = 160 imgs * 4 d-chunks, block = 256 (4 waves)
__global__ void k_conv(const float* __restrict__ S,
                       const float* __restrict__ w1, const float* __restrict__ b1,
                       const float* __restrict__ w2, const float* __restrict__ b2,
                       const float* __restrict__ wf, const float* __restrict__ bf,
                       float* __restrict__ score) {
    __shared__ float x1s[32 * 5][64];   // [c*5+i][lane]
    __shared__ float xfp[4][64];
    const int tid = threadIdx.x;
    const int lane = tid & 63;
    const int wv = __builtin_amdgcn_readfirstlane(tid >> 6);  // wave-uniform
    const int img = blockIdx.x >> 2, chunk = blockIdx.x & 3;
    const int d = chunk * 64 + lane;
    const bool act = d < DD;

    float in[5];
    const float* sp = S + (size_t)img * KK * DD + d;
#pragma unroll
    for (int j = 0; j < 5; j++) in[j] = act ? sp[j * DD] : 0.f;

    // phase 1: conv1 for channels c = wv*8 .. wv*8+7
#pragma unroll
    for (int ccc = 0; ccc < 8; ccc++) {
        int c = wv * 8 + ccc;
        float wl[5];
#pragma unroll
        for (int t = 0; t < 5; t++) wl[t] = w1[c * 5 + t];
        float bb = b1[c];
#pragma unroll
        for (int i = 0; i < 5; i++) {
            float a = bb;
#pragma unroll
            for (int t = 0; t < 5; t++) {
                int j = i + t - 2;
                if (j >= 0 && j < 5) a = fmaf(wl[t], in[j], a);
            }
            x1s[c * 5 + i][lane] = fmaxf(a, 0.f);
        }
    }
    __syncthreads();

    // phase 2: conv2 for o in [wv*16, wv*16+16) in 2 chunks of 8, + convf partial
    float xf = 0.f;
#pragma unroll
    for (int oc = 0; oc < 2; oc++) {
        const int ob = wv * 16 + oc * 8;
        const float* wb = w2 + (size_t)ob * 160;   // element (oo,c,t) at oo*160+c*5+t
        float acc[8][5];
#pragma unroll
        for (int oo = 0; oo < 8; oo++) {
            float bb = b2[ob + oo];
#pragma unroll
            for (int i = 0; i < 5; i++) acc[oo][i] = bb;
        }
        // double-buffered uniform weight block (8 oo x 5 taps)
        float wreg[8][5], wnxt[8][5];
#pragma unroll
        for (int oo = 0; oo < 8; oo++)
#pragma unroll
            for (int t = 0; t < 5; t++) wreg[oo][t] = wb[oo * 160 + t];

        for (int c = 0; c < 32; c++) {
            if (c < 31) {
#pragma unroll
                for (int oo = 0; oo < 8; oo++)
#pragma unroll
                    for (int t = 0; t < 5; t++)
                        wnxt[oo][t] = wb[oo * 160 + (c + 1) * 5 + t];
            }
            float xv[5];
#pragma unroll
            for (int j = 0; j < 5; j++) xv[j] = x1s[c * 5 + j][lane];
#pragma unroll
            for (int oo = 0; oo < 8; oo++)
#pragma unroll
                for (int t = 0; t < 5; t++) {
                    float w = wreg[oo][t];
#pragma unroll
                    for (int i = 0; i < 5; i++) {
                        int j = i + t - 2;
                        if (j >= 0 && j < 5) acc[oo][i] = fmaf(w, xv[j], acc[oo][i]);
                    }
                }
#pragma unroll
            for (int oo = 0; oo < 8; oo++)
#pragma unroll
                for (int t = 0; t < 5; t++) wreg[oo][t] = wnxt[oo][t];
        }
        // convf contribution (stride 5 -> taps are exactly positions 0..4)
#pragma unroll
        for (int oo = 0; oo < 8; oo++) {
            const float* wfp = wf + (ob + oo) * 5;
#pragma unroll
            for (int t = 0; t < 5; t++)
                xf = fmaf(wfp[t], fmaxf(acc[oo][t], 0.f), xf);
        }
    }
    xfp[wv][lane] = xf;
    __syncthreads();
    if (wv == 0 && act) {
        float v = bf[0] + xfp[0][lane] + xfp[1][lane] + xfp[2][lane] + xfp[3][lane];
        score[(size_t)img * DD + d] = fmaxf(v, 0.f) * 700.f;
    }
}

// ---------------- fused attention: tanh-logits + softmax + einsum + weighted L2 -----
// grid = B*NQ blocks, block = 256 (4 waves)
__global__ void k_att(const float* __restrict__ Sf, const float* __restrict__ Qf,
                      const float* __restrict__ S, const float* __restrict__ Q,
                      const float* __restrict__ sc, float* __restrict__ out) {
    __shared__ float Ls[NN * KK];
    const int tid = threadIdx.x, lane = tid & 63, wv = tid >> 6;
    const int bq = blockIdx.x;
    const int b = bq / NQ;
    const float LOG2E = 1.4426950408889634f;

    // ---- part 1: L[n,k] = sum_d tanh(Sf*Qf)  (Sf pre-scaled by 2*log2e) ----
    float qf[4];
    const float* qfp = Qf + (size_t)bq * DD;
#pragma unroll
    for (int i = 0; i < 4; i++) {
        int d = lane + 64 * i;
        qf[i] = (d < DD) ? qfp[d] : 0.f;
    }
    const float* sfb = Sf + (size_t)b * NN * KK * DD;
    for (int j = 0; j < 25; j++) {
        int idx = wv * 25 + j;   // n*5+k
        const float* sp = sfb + (size_t)idx * DD;
        float acc = 0.f;
#pragma unroll
        for (int i = 0; i < 4; i++) {
            int d = lane + 64 * i;
            float s = (d < DD) ? sp[d] : 0.f;
            float x = s * qf[i];
            float e = __builtin_amdgcn_exp2f(x);
            acc += 1.f - 2.f * __builtin_amdgcn_rcpf(e + 1.f);
        }
#pragma unroll
        for (int off = 32; off > 0; off >>= 1) acc += __shfl_xor(acc, off, 64);
        if (lane == 0) Ls[idx] = acc;
    }
    __syncthreads();

    // ---- part 2: softmax(K) + einsum + weighted L2 ----
    float qr[4];
    const float* qp = Q + (size_t)bq * DD;
#pragma unroll
    for (int i = 0; i < 4; i++) {
        int d = lane + 64 * i;
        qr[i] = (d < DD) ? qp[d] : 0.f;
    }
    for (int jn = 0; jn < 5; jn++) {
        int n = wv * 5 + jn;
        const float* lp = Ls + n * 5;
        float v0 = lp[0], v1 = lp[1], v2 = lp[2], v3 = lp[3], v4 = lp[4];
        float m = fmaxf(fmaxf(fmaxf(v0, v1), fmaxf(v2, v3)), v4);
        float e0 = __builtin_amdgcn_exp2f((v0 - m) * LOG2E);
        float e1 = __builtin_amdgcn_exp2f((v1 - m) * LOG2E);
        float e2 = __builtin_amdgcn_exp2f((v2 - m) * LOG2E);
        float e3 = __builtin_amdgcn_exp2f((v3 - m) * LOG2E);
        float e4 = __builtin_amdgcn_exp2f((v4 - m) * LOG2E);
        float inv = __builtin_amdgcn_rcpf(e0 + e1 + e2 + e3 + e4);
        float a0 = e0 * inv, a1 = e1 * inv, a2 = e2 * inv, a3 = e3 * inv, a4 = e4 * inv;
        const float* spn = S + (size_t)(b * NN + n) * KK * DD;
        const float* scp = sc + (size_t)(b * NN + n) * DD;
        float acc = 0.f;
#pragma unroll
        for (int i = 0; i < 4; i++) {
            int d = lane + 64 * i;
            if (d < DD) {
                float rep = a0 * spn[d] + a1 * spn[DD + d] + a2 * spn[2 * DD + d]
                          + a3 * spn[3 * DD + d] + a4 * spn[4 * DD + d];
                float df = rep - qr[i];
                acc = fmaf(df * df, scp[d], acc);
            }
        }
#pragma unroll
        for (int off = 32; off > 0; off >>= 1) acc += __shfl_xor(acc, off, 64);
        if (lane == 0) out[(size_t)bq * NN + n] = -acc;
    }
}

extern "C" void kernel_launch(void* const* d_in, const int* in_sizes, int n_in,
                              void* d_out, int out_size, void* d_ws, size_t ws_size,
                              hipStream_t stream) {
    const float* S       = (const float*)d_in[0];
    const float* Q       = (const float*)d_in[1];
    const float* fc_w    = (const float*)d_in[2];
    const float* fc_b    = (const float*)d_in[3];
    const float* conv1_w = (const float*)d_in[4];
    const float* conv1_b = (const float*)d_in[5];
    const float* conv2_w = (const float*)d_in[6];
    const float* conv2_b = (const float*)d_in[7];
    const float* convf_w = (const float*)d_in[8];
    const float* convf_b = (const float*)d_in[9];
    float* out = (float*)d_out;

    float* ws = (float*)d_ws;
    float* Wt = ws;                 // 52912
    float* Sf = Wt + 52912;         // 184000
    float* Qf = Sf + 184000;        // 368000
    float* sc = Qf + 368000;        // 36800

    const float TANH_SCALE = 2.8853900817779268f;  // 2*log2(e)

    k_transpose<<<208, 256, 0, stream>>>(fc_w, Wt);
    k_fc<<<(BB * NN * KK) / 4, 256, 0, stream>>>(S, Wt, fc_b, Sf, TANH_SCALE);
    k_fc<<<(BB * NQ) / 4, 256, 0, stream>>>(Q, Wt, fc_b, Qf, 1.0f);
    k_conv<<<BB * NN * 4, 256, 0, stream>>>(S, conv1_w, conv1_b, conv2_w, conv2_b,
                                            convf_w, convf_b, sc);
    k_att<<<BB * NQ, 256, 0, stream>>>(Sf, Qf, S, Q, sc, out);
    hipMemcpyAsync(out + (size_t)BB * NQ * NN, S,
                   (size_t)BB * NN * KK * DD * sizeof(float),
                   hipMemcpyDeviceToDevice, stream);
}

// Round 3
// 97.811 us; speedup vs baseline: 2.1077x; 1.2681x over previous
//
#include <hip/hip_runtime.h>
#include <hip/hip_bf16.h>

#define BB 8
#define NN 20
#define KK 5
#define DD 230
#define NQ 200

#define NB_CONV 640           // 160 imgs * 4 d-chunks
#define NB_TR   104           // transpose 230*230 over 512-thread blocks
#define NB_CP   90            // S passthrough copy as float4 (46000 float4s)

// ============ kernel A: conv chain + fc_w transpose + S passthrough copy ============
// 512 threads. Blocks [0,640): conv. [640,744): transpose. [744,834): copy.
__global__ void k_conv(const float* __restrict__ S,
                       const float* __restrict__ w1, const float* __restrict__ b1,
                       const float* __restrict__ w2, const float* __restrict__ b2,
                       const float* __restrict__ wf, const float* __restrict__ bf,
                       float* __restrict__ score,
                       const float* __restrict__ fc_w, float* __restrict__ Wt,
                       float* __restrict__ Scopy) {
    __shared__ float x1s[32 * 5][64];   // [c*5+i][lane]
    __shared__ float xfp[8][64];
    const int tid = threadIdx.x;
    const int bid = blockIdx.x;

    if (bid >= NB_CONV) {
        if (bid < NB_CONV + NB_TR) {
            int idx = (bid - NB_CONV) * 512 + tid;
            if (idx < DD * DD) {
                int i = idx / DD, j = idx % DD;
                Wt[j * DD + i] = fc_w[i * DD + j];
            }
        } else {
            int gidx = (bid - NB_CONV - NB_TR) * 512 + tid;
            if (gidx < (BB * NN * KK * DD) / 4 + 1) {
                if (gidx < 46000) {
                    const float4* src = (const float4*)S;
                    float4* dst = (float4*)Scopy;
                    dst[gidx] = src[gidx];
                }
            }
        }
        return;
    }

    const int lane = tid & 63;
    const int wv = __builtin_amdgcn_readfirstlane(tid >> 6);  // 0..7, wave-uniform
    const int img = bid >> 2, chunk = bid & 3;
    const int d = chunk * 64 + lane;
    const bool act = d < DD;

    float in[5];
    const float* sp = S + (size_t)img * KK * DD + d;
#pragma unroll
    for (int j = 0; j < 5; j++) in[j] = act ? sp[j * DD] : 0.f;

    // phase 1: conv1, each wave does channels c = wv*4 .. wv*4+3
#pragma unroll
    for (int ccc = 0; ccc < 4; ccc++) {
        int c = wv * 4 + ccc;
        float wl[5];
#pragma unroll
        for (int t = 0; t < 5; t++) wl[t] = w1[c * 5 + t];
        float bb = b1[c];
#pragma unroll
        for (int i = 0; i < 5; i++) {
            float a = bb;
#pragma unroll
            for (int t = 0; t < 5; t++) {
                int j = i + t - 2;
                if (j >= 0 && j < 5) a = fmaf(wl[t], in[j], a);
            }
            x1s[c * 5 + i][lane] = fmaxf(a, 0.f);
        }
    }
    __syncthreads();

    // phase 2: conv2 for o in [wv*8, wv*8+8) + convf partial
    float xf = 0.f;
    {
        const int ob = wv * 8;
        const float* wb = w2 + (size_t)ob * 160;   // (oo,c,t) at oo*160+c*5+t
        float acc[8][5];
#pragma unroll
        for (int oo = 0; oo < 8; oo++) {
            float bb = b2[ob + oo];
#pragma unroll
            for (int i = 0; i < 5; i++) acc[oo][i] = bb;
        }
        float wreg[8][5], wnxt[8][5];
#pragma unroll
        for (int oo = 0; oo < 8; oo++)
#pragma unroll
            for (int t = 0; t < 5; t++) wreg[oo][t] = wb[oo * 160 + t];

        for (int c = 0; c < 32; c++) {
            if (c < 31) {
#pragma unroll
                for (int oo = 0; oo < 8; oo++)
#pragma unroll
                    for (int t = 0; t < 5; t++)
                        wnxt[oo][t] = wb[oo * 160 + (c + 1) * 5 + t];
            }
            float xv[5];
#pragma unroll
            for (int j = 0; j < 5; j++) xv[j] = x1s[c * 5 + j][lane];
#pragma unroll
            for (int oo = 0; oo < 8; oo++)
#pragma unroll
                for (int t = 0; t < 5; t++) {
                    float w = wreg[oo][t];
#pragma unroll
                    for (int i = 0; i < 5; i++) {
                        int j = i + t - 2;
                        if (j >= 0 && j < 5) acc[oo][i] = fmaf(w, xv[j], acc[oo][i]);
                    }
                }
#pragma unroll
            for (int oo = 0; oo < 8; oo++)
#pragma unroll
                for (int t = 0; t < 5; t++) wreg[oo][t] = wnxt[oo][t];
        }
        // convf (stride 5 -> taps are exactly positions 0..4)
#pragma unroll
        for (int oo = 0; oo < 8; oo++) {
            const float* wfp = wf + (ob + oo) * 5;
#pragma unroll
            for (int t = 0; t < 5; t++)
                xf = fmaf(wfp[t], fmaxf(acc[oo][t], 0.f), xf);
        }
    }
    xfp[wv][lane] = xf;
    __syncthreads();
    if (wv == 0 && act) {
        float v = bf[0];
#pragma unroll
        for (int w8 = 0; w8 < 8; w8++) v += xfp[w8][lane];
        score[(size_t)img * DD + d] = fmaxf(v, 0.f) * 700.f;
    }
}

// ============ kernel B: fc for S (rows 0..799) and Q (rows 800..2399) ============
__global__ void k_fc(const float* __restrict__ S, const float* __restrict__ Q,
                     const float* __restrict__ wt, const float* __restrict__ bias,
                     float* __restrict__ Sf, float* __restrict__ Qf,
                     float tanh_scale) {
    const int c = threadIdx.x;
    const int cc = c < DD ? c : DD - 1;
    int r0 = blockIdx.x * 4;
    const float* in;
    float* out;
    float scale;
    if (r0 < BB * NN * KK) {
        in = S + (size_t)r0 * DD;
        out = Sf + (size_t)r0 * DD;
        scale = tanh_scale;
    } else {
        int r = r0 - BB * NN * KK;
        in = Q + (size_t)r * DD;
        out = Qf + (size_t)r * DD;
        scale = 1.0f;
    }
    const float* i0 = in;
    const float* i1 = i0 + DD;
    const float* i2 = i1 + DD;
    const float* i3 = i2 + DD;
    float a0 = 0.f, a1 = 0.f, a2 = 0.f, a3 = 0.f;
    for (int k = 0; k < DD; k++) {
        float w = wt[k * DD + cc];
        a0 = fmaf(i0[k], w, a0);
        a1 = fmaf(i1[k], w, a1);
        a2 = fmaf(i2[k], w, a2);
        a3 = fmaf(i3[k], w, a3);
    }
    if (c < DD) {
        float bb = bias[c];
        out[0 * DD + c] = (a0 + bb) * scale;
        out[1 * DD + c] = (a1 + bb) * scale;
        out[2 * DD + c] = (a2 + bb) * scale;
        out[3 * DD + c] = (a3 + bb) * scale;
    }
}

// ============ kernel C: tanh-logits + softmax + einsum + weighted L2 ============
__global__ void k_att(const float* __restrict__ Sf, const float* __restrict__ Qf,
                      const float* __restrict__ S, const float* __restrict__ Q,
                      const float* __restrict__ sc, float* __restrict__ out) {
    __shared__ float Ls[NN * KK];
    const int tid = threadIdx.x, lane = tid & 63, wv = tid >> 6;
    const int bq = blockIdx.x;
    const int b = bq / NQ;
    const float LOG2E = 1.4426950408889634f;

    float qf[4];
    const float* qfp = Qf + (size_t)bq * DD;
#pragma unroll
    for (int i = 0; i < 4; i++) {
        int d = lane + 64 * i;
        qf[i] = (d < DD) ? qfp[d] : 0.f;
    }
    const float* sfb = Sf + (size_t)b * NN * KK * DD;
    for (int j = 0; j < 25; j++) {
        int idx = wv * 25 + j;   // n*5+k
        const float* sp = sfb + (size_t)idx * DD;
        float acc = 0.f;
#pragma unroll
        for (int i = 0; i < 4; i++) {
            int d = lane + 64 * i;
            float s = (d < DD) ? sp[d] : 0.f;
            float x = s * qf[i];
            float e = __builtin_amdgcn_exp2f(x);
            acc += 1.f - 2.f * __builtin_amdgcn_rcpf(e + 1.f);
        }
#pragma unroll
        for (int off = 32; off > 0; off >>= 1) acc += __shfl_xor(acc, off, 64);
        if (lane == 0) Ls[idx] = acc;
    }
    __syncthreads();

    float qr[4];
    const float* qp = Q + (size_t)bq * DD;
#pragma unroll
    for (int i = 0; i < 4; i++) {
        int d = lane + 64 * i;
        qr[i] = (d < DD) ? qp[d] : 0.f;
    }
    for (int jn = 0; jn < 5; jn++) {
        int n = wv * 5 + jn;
        const float* lp = Ls + n * 5;
        float v0 = lp[0], v1 = lp[1], v2 = lp[2], v3 = lp[3], v4 = lp[4];
        float m = fmaxf(fmaxf(fmaxf(v0, v1), fmaxf(v2, v3)), v4);
        float e0 = __builtin_amdgcn_exp2f((v0 - m) * LOG2E);
        float e1 = __builtin_amdgcn_exp2f((v1 - m) * LOG2E);
        float e2 = __builtin_amdgcn_exp2f((v2 - m) * LOG2E);
        float e3 = __builtin_amdgcn_exp2f((v3 - m) * LOG2E);
        float e4 = __builtin_amdgcn_exp2f((v4 - m) * LOG2E);
        float inv = __builtin_amdgcn_rcpf(e0 + e1 + e2 + e3 + e4);
        float a0 = e0 * inv, a1 = e1 * inv, a2 = e2 * inv, a3 = e3 * inv, a4 = e4 * inv;
        const float* spn = S + (size_t)(b * NN + n) * KK * DD;
        const float* scp = sc + (size_t)(b * NN + n) * DD;
        float acc = 0.f;
#pragma unroll
        for (int i = 0; i < 4; i++) {
            int d = lane + 64 * i;
            if (d < DD) {
                float rep = a0 * spn[d] + a1 * spn[DD + d] + a2 * spn[2 * DD + d]
                          + a3 * spn[3 * DD + d] + a4 * spn[4 * DD + d];
                float df = rep - qr[i];
                acc = fmaf(df * df, scp[d], acc);
            }
        }
#pragma unroll
        for (int off = 32; off > 0; off >>= 1) acc += __shfl_xor(acc, off, 64);
        if (lane == 0) out[(size_t)bq * NN + n] = -acc;
    }
}

extern "C" void kernel_launch(void* const* d_in, const int* in_sizes, int n_in,
                              void* d_out, int out_size, void* d_ws, size_t ws_size,
                              hipStream_t stream) {
    const float* S       = (const float*)d_in[0];
    const float* Q       = (const float*)d_in[1];
    const float* fc_w    = (const float*)d_in[2];
    const float* fc_b    = (const float*)d_in[3];
    const float* conv1_w = (const float*)d_in[4];
    const float* conv1_b = (const float*)d_in[5];
    const float* conv2_w = (const float*)d_in[6];
    const float* conv2_b = (const float*)d_in[7];
    const float* convf_w = (const float*)d_in[8];
    const float* convf_b = (const float*)d_in[9];
    float* out = (float*)d_out;

    float* ws = (float*)d_ws;
    float* Wt = ws;                 // 52912
    float* Sf = Wt + 52912;         // 184000
    float* Qf = Sf + 184000;        // 368000
    float* sc = Qf + 368000;        // 36800

    const float TANH_SCALE = 2.8853900817779268f;  // 2*log2(e)

    k_conv<<<NB_CONV + NB_TR + NB_CP, 512, 0, stream>>>(
        S, conv1_w, conv1_b, conv2_w, conv2_b, convf_w, convf_b, sc,
        fc_w, Wt, out + (size_t)BB * NQ * NN);
    k_fc<<<(BB * NN * KK + BB * NQ) / 4, 256, 0, stream>>>(
        S, Q, Wt, fc_b, Sf, Qf, TANH_SCALE);
    k_att<<<BB * NQ, 256, 0, stream>>>(Sf, Qf, S, Q, sc, out);
}